// Round 1
// baseline (1449.036 us; speedup 1.0000x reference)
//
#include <hip/hip_runtime.h>
#include <hip/hip_bf16.h>
#include <math.h>

#define DIM_H 2048
#define VOCAB 32000
#define BK 32

typedef _Float16 half8v __attribute__((ext_vector_type(8)));
typedef _Float16 half4v __attribute__((ext_vector_type(4)));
typedef float floatx4 __attribute__((ext_vector_type(4)));

__device__ __forceinline__ void async_copy16(void* lds, const void* g) {
  __builtin_amdgcn_global_load_lds(
      (const __attribute__((address_space(1))) void*)g,
      (__attribute__((address_space(3))) void*)lds,
      16, 0, 0);
}

// ---------------- fp32 -> fp16 convert (vectorized x4) ----------------
__global__ void cvt_f32_f16(const float* __restrict__ src, _Float16* __restrict__ dst, long n) {
  long i = ((long)blockIdx.x * blockDim.x + threadIdx.x) * 4;
  if (i + 3 < n) {
    const float4 v = *(const float4*)(src + i);
    half4v h;
    h.x = (_Float16)v.x; h.y = (_Float16)v.y; h.z = (_Float16)v.z; h.w = (_Float16)v.w;
    *(half4v*)(dst + i) = h;
  }
}

// ---------------- pack targets: [chosen(1024) | rejected(1024)] ----------------
__global__ void pack_tgt(const int* __restrict__ tc, const int* __restrict__ tr, int* __restrict__ dst) {
  int t = blockIdx.x * blockDim.x + threadIdx.x;
  if (t < 2048) dst[t] = (t < 1024) ? tc[t] : tr[t - 1024];
}

// ---------------- fused GEMM + online sum-exp + target-logit extract ----------------
// X: [2048, 2048] fp16 (tokens x H), W: [32000, 2048] fp16 (vocab x H, i.e. B^T layout)
// per token row: sumexp[row] += sum_n exp(x.W_n + b_n); tgtlogit[row] = logit at target col
__global__ __launch_bounds__(256, 3)
void gemm_lse(const _Float16* __restrict__ X, const _Float16* __restrict__ W,
              const float* __restrict__ bias, const int* __restrict__ tgt,
              float* __restrict__ sumexp, float* __restrict__ tgtlogit) {
  __shared__ _Float16 sA[128 * BK];
  __shared__ _Float16 sB[128 * BK];

  const int tid = threadIdx.x;
  const int m0 = blockIdx.y << 7;   // token tile
  const int n0 = blockIdx.x << 7;   // vocab tile

  // staging: thread t covers 8 halves: row = t/4 (+64 for round 1), col8 = (t%4)*8
  const int ldr = tid >> 2;
  const int ldc = (tid & 3) << 3;
  const _Float16* gA = X + (size_t)(m0 + ldr) * DIM_H + ldc;
  const _Float16* gB = W + (size_t)(n0 + ldr) * DIM_H + ldc;
  _Float16* lA = sA + tid * 8;      // wave-uniform base + lane*16B, contiguous
  _Float16* lB = sB + tid * 8;

  const int lane = tid & 63;
  const int w = tid >> 6;           // 4 waves in 2x2 of 64x64
  const int wm = (w & 1) << 6;
  const int wn = (w >> 1) << 6;
  const int l15 = lane & 15;
  const int q = lane >> 4;

  int aoff[4], boff[4];
#pragma unroll
  for (int i = 0; i < 4; ++i) {
    aoff[i] = (wm + i * 16 + l15) * BK + q * 8;
    boff[i] = (wn + i * 16 + l15) * BK + q * 8;
  }

  floatx4 acc[4][4];
#pragma unroll
  for (int mi = 0; mi < 4; ++mi)
#pragma unroll
    for (int ni = 0; ni < 4; ++ni)
      acc[mi][ni] = 0.0f;

  for (int kt = 0; kt < DIM_H; kt += BK) {
    __syncthreads();  // previous iter's LDS reads done before overwrite
    async_copy16(lA,            gA + kt);
    async_copy16(lA + 64 * BK,  gA + kt + (size_t)64 * DIM_H);
    async_copy16(lB,            gB + kt);
    async_copy16(lB + 64 * BK,  gB + kt + (size_t)64 * DIM_H);
    __syncthreads();  // emits s_waitcnt vmcnt(0) before s_barrier -> LDS ready

    half8v af[4], bf[4];
#pragma unroll
    for (int i = 0; i < 4; ++i) {
      af[i] = *(const half8v*)(sA + aoff[i]);
      bf[i] = *(const half8v*)(sB + boff[i]);
    }
#pragma unroll
    for (int mi = 0; mi < 4; ++mi)
#pragma unroll
      for (int ni = 0; ni < 4; ++ni)
        acc[mi][ni] = __builtin_amdgcn_mfma_f32_16x16x32_f16(af[mi], bf[ni], acc[mi][ni], 0, 0, 0);
  }

  // epilogue: C/D layout col = lane&15, row = quad*4 + reg (m89/m91 verified)
  float bv[4];
#pragma unroll
  for (int ni = 0; ni < 4; ++ni) bv[ni] = bias[n0 + wn + ni * 16 + l15];

#pragma unroll
  for (int mi = 0; mi < 4; ++mi) {
#pragma unroll
    for (int reg = 0; reg < 4; ++reg) {
      const int row = m0 + wm + mi * 16 + q * 4 + reg;   // global token
      const int tv = tgt[row];
      float s = 0.f;
#pragma unroll
      for (int ni = 0; ni < 4; ++ni) {
        const float lg = acc[mi][ni][reg] + bv[ni];
        s += __expf(lg);
        if (tv == n0 + wn + ni * 16 + l15) tgtlogit[row] = lg;  // exactly one writer
      }
      // reduce across the 16 lanes of this quad (the 16 cols of the fragment)
      s += __shfl_xor(s, 1, 16);
      s += __shfl_xor(s, 2, 16);
      s += __shfl_xor(s, 4, 16);
      s += __shfl_xor(s, 8, 16);
      if (l15 == 0) atomicAdd(&sumexp[row], s);
    }
  }
}

// ---------------- final DPO reduction (1 block) ----------------
__global__ void dpo_reduce(const float* __restrict__ sumexp, const float* __restrict__ tgtlogit,
                           const int* __restrict__ tgt, float* __restrict__ out) {
  __shared__ float r[8];
  const int tid = threadIdx.x;
  const int j = tid >> 6;        // 8 waves: {polC,polR,refC,refR} x {b0,b1}
  const int lane = tid & 63;
  const int g = j >> 1, b = j & 1;
  float sum = 0.f;
  for (int s = lane; s < 512; s += 64) {
    const int slot = g * 1024 + b * 512 + s;
    const int tv = tgt[slot & 2047];
    if (tv != -100) sum += tgtlogit[slot] - logf(sumexp[slot]);
  }
#pragma unroll
  for (int m = 1; m < 64; m <<= 1) sum += __shfl_xor(sum, m, 64);
  if (lane == 0) r[j] = sum;
  __syncthreads();
  if (tid == 0) {
    const float beta = 0.1f;
    float pc[2] = {r[0], r[1]}, pr[2] = {r[2], r[3]};
    float rc[2] = {r[4], r[5]}, rr[2] = {r[6], r[7]};
    float loss = 0.f, cr[2], rj[2];
    for (int bb = 0; bb < 2; ++bb) {
      float d = beta * ((pc[bb] - pr[bb]) - (rc[bb] - rr[bb]));
      float ls = fminf(d, 0.f) - log1pf(expf(-fabsf(d)));  // log_sigmoid(d), stable
      loss += -ls;
      cr[bb] = beta * (pc[bb] - rc[bb]);
      rj[bb] = beta * (pr[bb] - rr[bb]);
    }
    out[0] = loss * 0.5f;
    out[1] = 0.5f * (cr[0] + cr[1]);
    out[2] = 0.5f * (rj[0] + rj[1]);
    out[3] = 0.5f * ((cr[0] - rj[0]) + (cr[1] - rj[1]));
    out[4] = 0.5f * ((cr[0] > rj[0] ? 1.f : 0.f) + (cr[1] > rj[1] ? 1.f : 0.f));
    out[5] = 0.f;
  }
}

extern "C" void kernel_launch(void* const* d_in, const int* in_sizes, int n_in,
                              void* d_out, int out_size, void* d_ws, size_t ws_size,
                              hipStream_t stream) {
  const float* x_c   = (const float*)d_in[0];
  const float* x_r   = (const float*)d_in[1];
  const float* rx_c  = (const float*)d_in[2];
  const float* rx_r  = (const float*)d_in[3];
  const float* Wt    = (const float*)d_in[4];
  const float* bias  = (const float*)d_in[5];
  const float* rWt   = (const float*)d_in[6];
  const float* rbias = (const float*)d_in[7];
  const int*   tc    = (const int*)d_in[8];
  const int*   tr    = (const int*)d_in[9];
  float* out = (float*)d_out;

  // workspace layout (~148 MB): W16 fp16 (reused for both weights) | X16 fp16 | scalars
  char* ws = (char*)d_ws;
  const size_t W16_B = (size_t)VOCAB * DIM_H * 2;      // 131,072,000
  const size_t X16_B = (size_t)4096 * DIM_H * 2;       //  16,777,216
  _Float16* W16   = (_Float16*)ws;
  _Float16* X16   = (_Float16*)(ws + W16_B);
  float*    sume  = (float*)(ws + W16_B + X16_B);                  // 4096 f32
  float*    tlog  = (float*)(ws + W16_B + X16_B + 16384);          // 4096 f32
  int*      tgt   = (int*)  (ws + W16_B + X16_B + 32768);          // 2048 i32

  hipMemsetAsync(sume, 0, 32768, stream);  // sumexp + tgtlogit
  pack_tgt<<<8, 256, 0, stream>>>(tc, tr, tgt);

  const long nx = 1024L * DIM_H;
  cvt_f32_f16<<<(unsigned)(nx / 4 / 256), 256, 0, stream>>>(x_c,  X16,          nx);
  cvt_f32_f16<<<(unsigned)(nx / 4 / 256), 256, 0, stream>>>(x_r,  X16 + nx,     nx);
  cvt_f32_f16<<<(unsigned)(nx / 4 / 256), 256, 0, stream>>>(rx_c, X16 + 2 * nx, nx);
  cvt_f32_f16<<<(unsigned)(nx / 4 / 256), 256, 0, stream>>>(rx_r, X16 + 3 * nx, nx);

  const long nw = (long)VOCAB * DIM_H;
  dim3 ggrid(VOCAB / 128, 2048 / 128);  // n fast-varying: each m-row streams W once

  cvt_f32_f16<<<(unsigned)(nw / 4 / 256), 256, 0, stream>>>(Wt, W16, nw);
  gemm_lse<<<ggrid, 256, 0, stream>>>(X16, W16, bias, tgt, sume, tlog);

  cvt_f32_f16<<<(unsigned)(nw / 4 / 256), 256, 0, stream>>>(rWt, W16, nw);
  gemm_lse<<<ggrid, 256, 0, stream>>>(X16 + 2 * nx, W16, rbias, tgt, sume + 2048, tlog + 2048);

  dpo_reduce<<<1, 512, 0, stream>>>(sume, tlog, tgt, out);
}

// Round 2
// 1203.627 us; speedup vs baseline: 1.2039x; 1.2039x over previous
//
#include <hip/hip_runtime.h>
#include <hip/hip_bf16.h>
#include <math.h>

#define DIM_H 2048
#define VOCAB 32000
#define BK 32

typedef _Float16 half8v __attribute__((ext_vector_type(8)));
typedef _Float16 half4v __attribute__((ext_vector_type(4)));
typedef float floatx4 __attribute__((ext_vector_type(4)));

__device__ __forceinline__ void async_copy16(void* lds, const void* g) {
  __builtin_amdgcn_global_load_lds(
      (const __attribute__((address_space(1))) void*)g,
      (__attribute__((address_space(3))) void*)lds,
      16, 0, 0);
}

// ---------------- fp32 -> fp16 convert (vectorized x4) ----------------
__global__ void cvt_f32_f16(const float* __restrict__ src, _Float16* __restrict__ dst, long n) {
  long i = ((long)blockIdx.x * blockDim.x + threadIdx.x) * 4;
  if (i + 3 < n) {
    const float4 v = *(const float4*)(src + i);
    half4v h;
    h.x = (_Float16)v.x; h.y = (_Float16)v.y; h.z = (_Float16)v.z; h.w = (_Float16)v.w;
    *(half4v*)(dst + i) = h;
  }
}

// ---------------- fused prep: W1 convert + 4 x converts + target pack ----------------
// blocks [0, 64000): W convert; [64000, 72192): x converts; [72192, 72200): pack
__global__ void prep(const float* __restrict__ xc, const float* __restrict__ xr,
                     const float* __restrict__ rxc, const float* __restrict__ rxr,
                     const float* __restrict__ W, _Float16* __restrict__ X16,
                     _Float16* __restrict__ W16,
                     const int* __restrict__ tc, const int* __restrict__ tr,
                     int* __restrict__ tgt) {
  const long b = blockIdx.x;
  if (b < 64000) {
    const long i = (b * 256 + threadIdx.x) * 4;
    const float4 v = *(const float4*)(W + i);
    half4v h;
    h.x = (_Float16)v.x; h.y = (_Float16)v.y; h.z = (_Float16)v.z; h.w = (_Float16)v.w;
    *(half4v*)(W16 + i) = h;
  } else if (b < 72192) {
    const long t = ((b - 64000) * 256 + threadIdx.x) * 4;   // 0 .. 8.388M
    const int seg = (int)(t >> 21);                          // 2^21 elems per x array
    const long off = t & ((1L << 21) - 1);
    const float* src = seg == 0 ? xc : seg == 1 ? xr : seg == 2 ? rxc : rxr;
    const float4 v = *(const float4*)(src + off);
    half4v h;
    h.x = (_Float16)v.x; h.y = (_Float16)v.y; h.z = (_Float16)v.z; h.w = (_Float16)v.w;
    *(half4v*)(X16 + t) = h;
  } else {
    const int t = (int)(b - 72192) * 256 + threadIdx.x;
    if (t < 2048) tgt[t] = (t < 1024) ? tc[t] : tr[t - 1024];
  }
}

// ---------------- fused GEMM + online sum-exp + target-logit extract ----------------
// X: [2048, 2048] fp16, W: [32000, 2048] fp16 (B^T layout). Grid (16 m-tiles, 250 n-tiles),
// m fast-varying: 16 consecutive blocks share one 512 KB W-slice -> W streamed from HBM once.
// LDS chunk-XOR swizzle (applied at stage via source permutation, since global_load_lds
// dest is lane-contiguous): LDS[row][slot] = G[row][slot ^ ((row>>1)&3)] -> b128 reads
// cover all 8 aligned bank-slots, 2-way (free).
__global__ __launch_bounds__(256, 4)
void gemm_lse(const _Float16* __restrict__ X, const _Float16* __restrict__ W,
              const float* __restrict__ bias, const int* __restrict__ tgt,
              float* __restrict__ sumexp, float* __restrict__ tgtlogit) {
  __shared__ _Float16 sA[128 * BK];
  __shared__ _Float16 sB[128 * BK];

  const int tid = threadIdx.x;
  const int m0 = blockIdx.x << 7;   // token tile (fast-varying for W reuse in L2)
  const int n0 = blockIdx.y << 7;   // vocab tile

  // staging: thread t covers row t>>2, global chunk (t&3) ^ ((t>>3)&3)  [swizzle]
  const int ldr = tid >> 2;
  const int ldc = (((tid & 3) ^ ((tid >> 3) & 3)) << 3);
  const _Float16* gA = X + (size_t)(m0 + ldr) * DIM_H + ldc;
  const _Float16* gB = W + (size_t)(n0 + ldr) * DIM_H + ldc;
  _Float16* lA = sA + tid * 8;      // wave-uniform base + lane*16B (HW requirement)
  _Float16* lB = sB + tid * 8;

  const int lane = tid & 63;
  const int w = tid >> 6;           // 4 waves in 2x2 of 64x64
  const int wm = (w & 1) << 6;
  const int wn = (w >> 1) << 6;
  const int l15 = lane & 15;
  const int q = lane >> 4;
  const int swz = (l15 >> 1) & 3;   // row-derived swizzle, uniform across frags

  int aoff[4], boff[4];
#pragma unroll
  for (int i = 0; i < 4; ++i) {
    aoff[i] = (wm + i * 16 + l15) * BK + ((q ^ swz) << 3);
    boff[i] = (wn + i * 16 + l15) * BK + ((q ^ swz) << 3);
  }

  floatx4 acc[4][4];
#pragma unroll
  for (int mi = 0; mi < 4; ++mi)
#pragma unroll
    for (int ni = 0; ni < 4; ++ni)
      acc[mi][ni] = 0.0f;

  for (int kt = 0; kt < DIM_H; kt += BK) {
    __syncthreads();  // previous iter's LDS reads done before overwrite
    async_copy16(lA,            gA + kt);
    async_copy16(lA + 64 * BK,  gA + kt + (size_t)64 * DIM_H);
    async_copy16(lB,            gB + kt);
    async_copy16(lB + 64 * BK,  gB + kt + (size_t)64 * DIM_H);
    __syncthreads();  // s_waitcnt vmcnt(0) before s_barrier -> LDS ready

    half8v af[4], bf[4];
#pragma unroll
    for (int i = 0; i < 4; ++i) {
      af[i] = *(const half8v*)(sA + aoff[i]);
      bf[i] = *(const half8v*)(sB + boff[i]);
    }
#pragma unroll
    for (int mi = 0; mi < 4; ++mi)
#pragma unroll
      for (int ni = 0; ni < 4; ++ni)
        acc[mi][ni] = __builtin_amdgcn_mfma_f32_16x16x32_f16(af[mi], bf[ni], acc[mi][ni], 0, 0, 0);
  }

  // epilogue: C/D layout col = lane&15, row = quad*4 + reg (m89/m91 verified)
  float bv[4];
#pragma unroll
  for (int ni = 0; ni < 4; ++ni) bv[ni] = bias[n0 + wn + ni * 16 + l15];

#pragma unroll
  for (int mi = 0; mi < 4; ++mi) {
#pragma unroll
    for (int reg = 0; reg < 4; ++reg) {
      const int row = m0 + wm + mi * 16 + q * 4 + reg;   // global token
      const int tv = tgt[row];
      float s = 0.f;
#pragma unroll
      for (int ni = 0; ni < 4; ++ni) {
        const float lg = acc[mi][ni][reg] + bv[ni];
        s += __expf(lg);
        if (tv == n0 + wn + ni * 16 + l15) tgtlogit[row] = lg;  // exactly one writer
      }
      // reduce across the 16 lanes of this quad (the 16 cols of the fragment)
      s += __shfl_xor(s, 1, 16);
      s += __shfl_xor(s, 2, 16);
      s += __shfl_xor(s, 4, 16);
      s += __shfl_xor(s, 8, 16);
      if (l15 == 0) atomicAdd(&sumexp[row], s);
    }
  }
}

// ---------------- final DPO reduction (1 block) ----------------
__global__ void dpo_reduce(const float* __restrict__ sumexp, const float* __restrict__ tgtlogit,
                           const int* __restrict__ tgt, float* __restrict__ out) {
  __shared__ float r[8];
  const int tid = threadIdx.x;
  const int j = tid >> 6;        // 8 waves: {polC,polR,refC,refR} x {b0,b1}
  const int lane = tid & 63;
  const int g = j >> 1, b = j & 1;
  float sum = 0.f;
  for (int s = lane; s < 512; s += 64) {
    const int slot = g * 1024 + b * 512 + s;
    const int tv = tgt[slot & 2047];
    if (tv != -100) sum += tgtlogit[slot] - logf(sumexp[slot]);
  }
#pragma unroll
  for (int m = 1; m < 64; m <<= 1) sum += __shfl_xor(sum, m, 64);
  if (lane == 0) r[j] = sum;
  __syncthreads();
  if (tid == 0) {
    const float beta = 0.1f;
    float pc[2] = {r[0], r[1]}, pr[2] = {r[2], r[3]};
    float rc[2] = {r[4], r[5]}, rr[2] = {r[6], r[7]};
    float loss = 0.f, cr[2], rj[2];
    for (int bb = 0; bb < 2; ++bb) {
      float d = beta * ((pc[bb] - pr[bb]) - (rc[bb] - rr[bb]));
      float ls = fminf(d, 0.f) - log1pf(expf(-fabsf(d)));  // log_sigmoid(d), stable
      loss += -ls;
      cr[bb] = beta * (pc[bb] - rc[bb]);
      rj[bb] = beta * (pr[bb] - rr[bb]);
    }
    out[0] = loss * 0.5f;
    out[1] = 0.5f * (cr[0] + cr[1]);
    out[2] = 0.5f * (rj[0] + rj[1]);
    out[3] = 0.5f * ((cr[0] - rj[0]) + (cr[1] - rj[1]));
    out[4] = 0.5f * ((cr[0] > rj[0] ? 1.f : 0.f) + (cr[1] > rj[1] ? 1.f : 0.f));
    out[5] = 0.f;
  }
}

extern "C" void kernel_launch(void* const* d_in, const int* in_sizes, int n_in,
                              void* d_out, int out_size, void* d_ws, size_t ws_size,
                              hipStream_t stream) {
  const float* x_c   = (const float*)d_in[0];
  const float* x_r   = (const float*)d_in[1];
  const float* rx_c  = (const float*)d_in[2];
  const float* rx_r  = (const float*)d_in[3];
  const float* Wt    = (const float*)d_in[4];
  const float* bias  = (const float*)d_in[5];
  const float* rWt   = (const float*)d_in[6];
  const float* rbias = (const float*)d_in[7];
  const int*   tc    = (const int*)d_in[8];
  const int*   tr    = (const int*)d_in[9];
  float* out = (float*)d_out;

  // workspace layout (~148 MB): W16 fp16 (reused for both weights) | X16 fp16 | scalars
  char* ws = (char*)d_ws;
  const size_t W16_B = (size_t)VOCAB * DIM_H * 2;      // 131,072,000
  const size_t X16_B = (size_t)4096 * DIM_H * 2;       //  16,777,216
  _Float16* W16   = (_Float16*)ws;
  _Float16* X16   = (_Float16*)(ws + W16_B);
  float*    sume  = (float*)(ws + W16_B + X16_B);                  // 4096 f32
  float*    tlog  = (float*)(ws + W16_B + X16_B + 16384);          // 4096 f32
  int*      tgt   = (int*)  (ws + W16_B + X16_B + 32768);          // 2048 i32

  hipMemsetAsync(sume, 0, 32768, stream);  // sumexp + tgtlogit

  prep<<<72200, 256, 0, stream>>>(x_c, x_r, rx_c, rx_r, Wt, X16, W16, tc, tr, tgt);

  const long nx = 1024L * DIM_H;
  const long nw = (long)VOCAB * DIM_H;
  dim3 ggrid(2048 / 128, VOCAB / 128);  // m fast-varying: W slice reused by 16 blocks

  gemm_lse<<<ggrid, 256, 0, stream>>>(X16, W16, bias, tgt, sume, tlog);

  cvt_f32_f16<<<(unsigned)(nw / 4 / 256), 256, 0, stream>>>(rWt, W16, nw);
  gemm_lse<<<ggrid, 256, 0, stream>>>(X16 + 2 * nx, W16, rbias, tgt, sume + 2048, tlog + 2048);

  dpo_reduce<<<1, 512, 0, stream>>>(sume, tlog, tgt, out);
}